// Round 7
// baseline (2362.107 us; speedup 1.0000x reference)
//
#include <hip/hip_runtime.h>
#include <stdint.h>

typedef short short8 __attribute__((ext_vector_type(8)));
typedef float floatx4 __attribute__((ext_vector_type(4)));

#define BK 256   // nodes per bucket

static __device__ __forceinline__ float bflo(unsigned int u) {
    union { unsigned int i; float f; } v; v.i = u << 16; return v.f;
}
static __device__ __forceinline__ float bfhi(unsigned int u) {
    union { unsigned int i; float f; } v; v.i = u & 0xffff0000u; return v.f;
}
static __device__ __forceinline__ float bf2f(unsigned short u) {
    union { unsigned int i; float f; } v; v.i = ((unsigned int)u) << 16; return v.f;
}
static __device__ __forceinline__ unsigned short f2bf(float f) {
    union { float f; unsigned int i; } v; v.f = f;
    unsigned int u = v.i;
    unsigned int r = u + 0x7fffu + ((u >> 16) & 1u);
    return (unsigned short)(r >> 16);
}

// ---------------- CSR-lite build: coarse bucket sort only ----------------

__global__ void k_zero_cnt(int* bucket_cnt, int K) {
    int i = blockIdx.x * 256 + threadIdx.x;
    if (i < K) bucket_cnt[i] = 0;
}

// coarse histogram of dst>>8; per-wave LDS hists to cut same-address contention
__global__ __launch_bounds__(256) void k_hist(const int* __restrict__ dst, int* bucket_cnt,
                                              int E, int N, int K) {
    __shared__ int h[4][512];
    int t = threadIdx.x, w = t >> 6;
    for (int i = t; i < 4 * 512; i += 256) ((int*)h)[i] = 0;
    __syncthreads();
    int per = (E + gridDim.x - 1) / gridDim.x;
    int lo = blockIdx.x * per, hi = min(lo + per, E);
    for (int e = lo + t; e < hi; e += 256) {
        unsigned int d = (unsigned int)dst[e];
        if (d < (unsigned int)N) atomicAdd(&h[w][d >> 8], 1);
    }
    __syncthreads();
    for (int i = t; i < K; i += 256) {
        int c = h[0][i] + h[1][i] + h[2][i] + h[3][i];
        if (c) atomicAdd(&bucket_cnt[i], c);
    }
}

// single block: exclusive scan of K bucket counts (K <= 512)
__global__ void k_scanK(const int* __restrict__ bucket_cnt, int* bucket_off, int* bucket_cur,
                        int K) {
    __shared__ int s[512];
    int t = threadIdx.x;
    int v = (t < K) ? bucket_cnt[t] : 0;
    s[t] = v; __syncthreads();
    for (int off = 1; off < 512; off <<= 1) {
        int x = (t >= off) ? s[t - off] : 0;
        __syncthreads();
        s[t] += x;
        __syncthreads();
    }
    if (t < K) { bucket_off[t] = s[t] - v; bucket_cur[t] = s[t] - v; }
    if (t == K - 1) bucket_off[K] = s[t];
}

// bucket-sort edges into packed 4B entries (src<<8)|(dst&255); per-wave hists/cursors
__global__ __launch_bounds__(256) void k_binscatter(const int* __restrict__ src,
                                                    const int* __restrict__ dst,
                                                    int* bucket_cur, unsigned int* __restrict__ tmp,
                                                    int E, int N, int K) {
    __shared__ int h[4][512];
    int t = threadIdx.x, w = t >> 6;
    for (int i = t; i < 4 * 512; i += 256) ((int*)h)[i] = 0;
    __syncthreads();
    int per = (E + gridDim.x - 1) / gridDim.x;
    int lo = blockIdx.x * per, hi = min(lo + per, E);
    for (int e = lo + t; e < hi; e += 256) {
        unsigned int d = (unsigned int)dst[e];
        if (d < (unsigned int)N) atomicAdd(&h[w][d >> 8], 1);
    }
    __syncthreads();
    for (int k = t; k < K; k += 256) {
        int c0 = h[0][k], c1 = h[1][k], c2 = h[2][k], c3 = h[3][k];
        int tot = c0 + c1 + c2 + c3;
        int base = tot ? atomicAdd(&bucket_cur[k], tot) : 0;
        h[0][k] = base; h[1][k] = base + c0; h[2][k] = base + c0 + c1;
        h[3][k] = base + c0 + c1 + c2;
    }
    __syncthreads();
    for (int e = lo + t; e < hi; e += 256) {
        unsigned int d = (unsigned int)dst[e];
        if (d < (unsigned int)N) {
            unsigned int sv = (unsigned int)src[e];
            if (sv >= (unsigned int)N) sv = 0;
            int p = atomicAdd(&h[w][d >> 8], 1);
            tmp[p] = (sv << 8) | (d & 255u);
        }
    }
}

// per bucket: node degrees -> dinv (per-wave LDS hists)
__global__ __launch_bounds__(256) void k_deg(const unsigned int* __restrict__ tmp,
                                             const int* __restrict__ bucket_off,
                                             float* __restrict__ dinv, int N) {
    __shared__ int h[4][256];
    int t = threadIdx.x, w = t >> 6;
    for (int i = t; i < 4 * 256; i += 256) ((int*)h)[i] = 0;
    __syncthreads();
    int b = blockIdx.x;
    int lo = bucket_off[b], hi = bucket_off[b + 1];
    for (int e = lo + t; e < hi; e += 256) atomicAdd(&h[w][tmp[e] & 255u], 1);
    __syncthreads();
    int node = b * BK + t;
    if (node < N) {
        int deg = h[0][t] + h[1][t] + h[2][t] + h[3][t];
        dinv[node] = rsqrtf((float)(deg + 1));
    }
}

// ---------------- W pre-convert: fp32 [K][Nc] -> bf16 transposed [Nc][K] ----------------

__global__ void k_wconv(const float* __restrict__ W, unsigned short* __restrict__ Wt,
                        int K, int Nc) {
    int i = blockIdx.x * 256 + threadIdx.x;
    if (i < K * Nc) {
        int k = i / Nc, n = i % Nc;
        Wt[n * K + k] = f2bf(W[i]);
    }
}

// ---------------- GEMM: out[M,NOUT] = X[M,128] @ W[128,NOUT], K=128 ----------------
// Wbf bf16 pre-transposed [NOUT][128]. X: fp32 row-major (XF32) or bf16 sliced [8][M][16]
// (ASLICED). Out: bf16 sliced [NT][M][16] (OSLICED) or fp32 row-major.

template <int NOUT, bool SCALE, bool BIAS, bool XF32, bool ASLICED, bool OSLICED>
__global__ __launch_bounds__(256, 2) void k_gemm(
    const void* __restrict__ Xv, const unsigned short* __restrict__ Wbf,
    const float* __restrict__ bias, const float* __restrict__ dinv,
    void* __restrict__ outv, int M) {
    // Wl[n*136 + k]; stride 136 (272B ≡ 4 banks mod 32 -> 2-way conflict = free)
    __shared__ __align__(16) unsigned short Wl[NOUT * 136];
    int t = threadIdx.x;
    for (int c = t; c < NOUT * 16; c += 256) {
        short8 v = *(const short8*)(Wbf + (size_t)c * 8);
        *(short8*)(&Wl[(c >> 4) * 136 + (c & 15) * 8]) = v;
    }
    __syncthreads();

    int wave = t >> 6, lane = t & 63;
    int quad = lane >> 4, l16 = lane & 15;
    constexpr int NT = NOUT / 16;

    int m0 = blockIdx.x * 64 + wave * 16;
    int mr = m0 + l16;
    int mrc = mr < M ? mr : M - 1;

    floatx4 acc[NT];
#pragma unroll
    for (int i = 0; i < NT; i++) acc[i] = (floatx4){0.f, 0.f, 0.f, 0.f};

#pragma unroll
    for (int kc = 0; kc < 4; kc++) {
        short8 a;
        if (XF32) {
            const float* X = (const float*)Xv;
            const float* p = X + (size_t)mrc * 128 + kc * 32 + quad * 8;
            float4 xa = *(const float4*)p;
            float4 xb = *(const float4*)(p + 4);
            a[0] = (short)f2bf(xa.x); a[1] = (short)f2bf(xa.y);
            a[2] = (short)f2bf(xa.z); a[3] = (short)f2bf(xa.w);
            a[4] = (short)f2bf(xb.x); a[5] = (short)f2bf(xb.y);
            a[6] = (short)f2bf(xb.z); a[7] = (short)f2bf(xb.w);
        } else if (ASLICED) {
            const unsigned short* X = (const unsigned short*)Xv;
            int slice = kc * 2 + (quad >> 1);
            a = *(const short8*)(X + ((size_t)slice * M + mrc) * 16 + (quad & 1) * 8);
        } else {
            const unsigned short* X = (const unsigned short*)Xv;
            a = *(const short8*)(X + (size_t)mrc * 128 + kc * 32 + quad * 8);
        }
#pragma unroll
        for (int nt = 0; nt < NT; nt++) {
            short8 b = *(const short8*)(&Wl[(nt * 16 + l16) * 136 + kc * 32 + quad * 8]);
            acc[nt] = __builtin_amdgcn_mfma_f32_16x16x32_bf16(a, b, acc[nt], 0, 0, 0);
        }
    }

    // C layout: col = l16, row (within 16) = quad*4 + i
#pragma unroll
    for (int i = 0; i < 4; i++) {
        int r = m0 + quad * 4 + i;
        if (r >= M) continue;
        float sc = SCALE ? dinv[r] : 1.0f;
#pragma unroll
        for (int nt = 0; nt < NT; nt++) {
            int n = nt * 16 + l16;
            float v = acc[nt][i] * sc;
            if (BIAS) v += bias[n];
            if (OSLICED) {
                ((unsigned short*)outv)[((size_t)nt * M + r) * 16 + l16] = f2bf(v);
            } else {
                ((float*)outv)[(size_t)r * NOUT + n] = v;
            }
        }
    }
}

// ---------------- Bucket-sliced aggregation ----------------
// block = (bucket b, slice s = blockIdx&7 -> XCD-affine). LDS fp32 acc[256 nodes][16ch]
// (stride 17 dwords). Stream bucket edges; 8 edges x 8 ch-pairs per wave; ds_add_f32.
// Epilogue: At[s][node][16] = relu(dinv*(acc + Hst[s][node]) + bias[s*16..]).

__global__ __launch_bounds__(256, 8) void k_agg_bucket(
    const unsigned short* __restrict__ Hst, const unsigned int* __restrict__ tmp,
    const int* __restrict__ bucket_off, const float* __restrict__ dinv,
    const float* __restrict__ bias, unsigned short* __restrict__ At, int N) {
    __shared__ float acc[BK * 17];
    int s = blockIdx.x & 7;
    int b = blockIdx.x >> 3;
    int t = threadIdx.x;
#pragma unroll
    for (int i = 0; i < 17; i++) acc[i * 256 + t] = 0.f;
    __syncthreads();

    int lo = bucket_off[b], hi = bucket_off[b + 1];
    const unsigned short* Ts = Hst + (size_t)s * N * 16;
    int wave = t >> 6, eg = (t >> 3) & 7, cp = t & 7;

    for (int e = lo + wave * 8 + eg; e < hi; e += 32) {
        unsigned int p = tmp[e];
        int srcn = p >> 8;
        int d8 = p & 255u;
        unsigned int u = *(const unsigned int*)(Ts + (size_t)srcn * 16 + cp * 2);
        atomicAdd(&acc[d8 * 17 + cp * 2], bflo(u));
        atomicAdd(&acc[d8 * 17 + cp * 2 + 1], bfhi(u));
    }
    __syncthreads();

    int node = b * BK + t;
    if (node < N) {
        float di = dinv[node];
        const unsigned short* selfp = Ts + (size_t)node * 16;
        short8 sv0 = *(const short8*)selfp;
        short8 sv1 = *(const short8*)(selfp + 8);
        unsigned short o[16];
#pragma unroll
        for (int c = 0; c < 8; c++) {
            float v = acc[t * 17 + c] + bf2f((unsigned short)sv0[c]);
            o[c] = f2bf(fmaxf(fmaf(di, v, bias[s * 16 + c]), 0.f));
        }
#pragma unroll
        for (int c = 0; c < 8; c++) {
            float v = acc[t * 17 + 8 + c] + bf2f((unsigned short)sv1[c]);
            o[8 + c] = f2bf(fmaxf(fmaf(di, v, bias[s * 16 + 8 + c]), 0.f));
        }
        unsigned short* op = At + ((size_t)s * N + node) * 16;
        *(short8*)op = *(short8*)o;
        *(short8*)(op + 8) = *(short8*)(o + 8);
    }
}

// ---------------- launch ----------------

extern "C" void kernel_launch(void* const* d_in, const int* in_sizes, int n_in,
                              void* d_out, int out_size, void* d_ws, size_t ws_size,
                              hipStream_t stream) {
    const float* x  = (const float*)d_in[0];
    const int* ei   = (const int*)d_in[1];
    const float* W1 = (const float*)d_in[2];
    const float* b1 = (const float*)d_in[3];
    const float* W2 = (const float*)d_in[4];
    const float* b2 = (const float*)d_in[5];
    const float* Wf = (const float*)d_in[6];
    const float* bf = (const float*)d_in[7];

    int N = in_sizes[0] / 128;
    int E = in_sizes[1] / 2;
    const int* src = ei;
    const int* dst = ei + E;
    int K = (N + BK - 1) / BK;
    if (N >= (1 << 24) || K > 512) return;  // packing/scan assumptions

    size_t need = 0;
    auto pad = [](size_t b) { return (b + 255) & ~(size_t)255; };
    size_t o_bcnt = need; need += pad(512 * 4);
    size_t o_boff = need; need += pad(513 * 4);
    size_t o_bcur = need; need += pad(512 * 4);
    size_t o_dinv = need; need += pad((size_t)N * 4);
    size_t o_wbf  = need; need += pad((16384 + 16384 + 8192) * 2);
    size_t o_tmp  = need; need += pad((size_t)E * 4);
    size_t o_hs   = need; need += pad((size_t)N * 128 * 2);
    size_t o_a    = need; need += pad((size_t)N * 128 * 2);
    if (ws_size < need) return;

    char* ws = (char*)d_ws;
    int* bucket_cnt = (int*)(ws + o_bcnt);
    int* bucket_off = (int*)(ws + o_boff);
    int* bucket_cur = (int*)(ws + o_bcur);
    float* dinv     = (float*)(ws + o_dinv);
    unsigned short* wb1 = (unsigned short*)(ws + o_wbf);
    unsigned short* wb2 = wb1 + 16384;
    unsigned short* wbf = wb2 + 16384;
    unsigned int* tmp   = (unsigned int*)(ws + o_tmp);
    unsigned short* Hst = (unsigned short*)(ws + o_hs);
    unsigned short* At  = (unsigned short*)(ws + o_a);

    // W pre-convert (tiny)
    k_wconv<<<64, 256, 0, stream>>>(W1, wb1, 128, 128);
    k_wconv<<<64, 256, 0, stream>>>(W2, wb2, 128, 128);
    k_wconv<<<32, 256, 0, stream>>>(Wf, wbf, 128, 64);

    // bucket sort + degrees
    k_zero_cnt<<<2, 256, 0, stream>>>(bucket_cnt, 512);
    k_hist<<<256, 256, 0, stream>>>(dst, bucket_cnt, E, N, K);
    k_scanK<<<1, 512, 0, stream>>>(bucket_cnt, bucket_off, bucket_cur, K);
    k_binscatter<<<256, 256, 0, stream>>>(src, dst, bucket_cur, tmp, E, N, K);
    k_deg<<<K, 256, 0, stream>>>(tmp, bucket_off, dinv, N);

    int GB = (N + 63) / 64;
    int GA = K * 8;

    k_gemm<128, true, false, true, false, true><<<GB, 256, 0, stream>>>(x, wb1, nullptr, dinv, Hst, N);
    k_agg_bucket<<<GA, 256, 0, stream>>>(Hst, tmp, bucket_off, dinv, b1, At, N);
    k_gemm<128, true, false, false, true, true><<<GB, 256, 0, stream>>>(At, wb2, nullptr, dinv, Hst, N);
    k_agg_bucket<<<GA, 256, 0, stream>>>(Hst, tmp, bucket_off, dinv, b2, At, N);
    k_gemm<64, false, true, false, true, false><<<GB, 256, 0, stream>>>(At, wbf, bf, nullptr, d_out, N);
}

// Round 8
// 340.752 us; speedup vs baseline: 6.9321x; 6.9321x over previous
//
#include <hip/hip_runtime.h>
#include <stdint.h>

typedef short short8 __attribute__((ext_vector_type(8)));
typedef float floatx4 __attribute__((ext_vector_type(4)));

#define BK 256   // nodes per bucket

static __device__ __forceinline__ float bflo(unsigned int u) {
    union { unsigned int i; float f; } v; v.i = u << 16; return v.f;
}
static __device__ __forceinline__ float bfhi(unsigned int u) {
    union { unsigned int i; float f; } v; v.i = u & 0xffff0000u; return v.f;
}
static __device__ __forceinline__ unsigned short f2bf(float f) {
    union { float f; unsigned int i; } v; v.f = f;
    unsigned int u = v.i;
    unsigned int r = u + 0x7fffu + ((u >> 16) & 1u);
    return (unsigned short)(r >> 16);
}

// ---------------- CSR build: two-level counting sort, packed 4B entries ----------------

__global__ void k_zero_cnt(int* bucket_cnt, int K) {
    int i = blockIdx.x * 256 + threadIdx.x;
    if (i < K) bucket_cnt[i] = 0;
}

// coarse histogram of dst>>8; per-wave LDS hists cut same-address contention
__global__ __launch_bounds__(256) void k_hist(const int* __restrict__ dst, int* bucket_cnt,
                                              int E, int N, int K) {
    __shared__ int h[4][512];
    int t = threadIdx.x, w = t >> 6;
    for (int i = t; i < 4 * 512; i += 256) ((int*)h)[i] = 0;
    __syncthreads();
    int per = (E + gridDim.x - 1) / gridDim.x;
    int lo = blockIdx.x * per, hi = min(lo + per, E);
    for (int e = lo + t; e < hi; e += 256) {
        unsigned int d = (unsigned int)dst[e];
        if (d < (unsigned int)N) atomicAdd(&h[w][d >> 8], 1);
    }
    __syncthreads();
    for (int i = t; i < K; i += 256) {
        int c = h[0][i] + h[1][i] + h[2][i] + h[3][i];
        if (c) atomicAdd(&bucket_cnt[i], c);
    }
}

// single block: exclusive scan of K bucket counts (K <= 512); sentinel row_start[N]
__global__ void k_scanK(const int* __restrict__ bucket_cnt, int* bucket_off, int* bucket_cur,
                        int* row_start, int K, int N) {
    __shared__ int s[512];
    int t = threadIdx.x;
    int v = (t < K) ? bucket_cnt[t] : 0;
    s[t] = v; __syncthreads();
    for (int off = 1; off < 512; off <<= 1) {
        int x = (t >= off) ? s[t - off] : 0;
        __syncthreads();
        s[t] += x;
        __syncthreads();
    }
    if (t < K) { bucket_off[t] = s[t] - v; bucket_cur[t] = s[t] - v; }
    if (t == K - 1) { bucket_off[K] = s[t]; row_start[N] = s[t]; }
}

// bucket-sort edges into packed 4B entries (src<<8)|(dst&255); per-wave hists/cursors
__global__ __launch_bounds__(256) void k_binscatter(const int* __restrict__ src,
                                                    const int* __restrict__ dst,
                                                    int* bucket_cur, unsigned int* __restrict__ tmp,
                                                    int E, int N, int K) {
    __shared__ int h[4][512];
    int t = threadIdx.x, w = t >> 6;
    for (int i = t; i < 4 * 512; i += 256) ((int*)h)[i] = 0;
    __syncthreads();
    int per = (E + gridDim.x - 1) / gridDim.x;
    int lo = blockIdx.x * per, hi = min(lo + per, E);
    for (int e = lo + t; e < hi; e += 256) {
        unsigned int d = (unsigned int)dst[e];
        if (d < (unsigned int)N) atomicAdd(&h[w][d >> 8], 1);
    }
    __syncthreads();
    for (int k = t; k < K; k += 256) {
        int c0 = h[0][k], c1 = h[1][k], c2 = h[2][k], c3 = h[3][k];
        int tot = c0 + c1 + c2 + c3;
        int base = tot ? atomicAdd(&bucket_cur[k], tot) : 0;
        h[0][k] = base; h[1][k] = base + c0; h[2][k] = base + c0 + c1;
        h[3][k] = base + c0 + c1 + c2;
    }
    __syncthreads();
    for (int e = lo + t; e < hi; e += 256) {
        unsigned int d = (unsigned int)dst[e];
        if (d < (unsigned int)N) {
            unsigned int sv = (unsigned int)src[e];
            if (sv >= (unsigned int)N) sv = 0;
            int p = atomicAdd(&h[w][d >> 8], 1);
            tmp[p] = (sv << 8) | (d & 255u);
        }
    }
}

// one block per bucket: degrees (per-wave hists) -> scan -> dst-sorted csr + dinv
__global__ __launch_bounds__(256) void k_fine(const unsigned int* __restrict__ tmp,
                                              const int* __restrict__ bucket_off,
                                              int* __restrict__ row_start, float* __restrict__ dinv,
                                              int* __restrict__ csr, int N) {
    __shared__ int deg4[4][BK];
    __shared__ int scn[BK];
    __shared__ int cur[BK];
    int b = blockIdx.x, t = threadIdx.x, w = t >> 6;
    int lo = bucket_off[b], hi = bucket_off[b + 1];
    for (int i = t; i < 4 * BK; i += 256) ((int*)deg4)[i] = 0;
    __syncthreads();
    for (int e = lo + t; e < hi; e += 256) atomicAdd(&deg4[w][tmp[e] & 255u], 1);
    __syncthreads();
    int v = deg4[0][t] + deg4[1][t] + deg4[2][t] + deg4[3][t];
    scn[t] = v; __syncthreads();
    for (int off = 1; off < 256; off <<= 1) {
        int x = (t >= off) ? scn[t - off] : 0;
        __syncthreads();
        scn[t] += x;
        __syncthreads();
    }
    int rs = lo + scn[t] - v;
    cur[t] = rs;
    int node = b * BK + t;
    if (node < N) { row_start[node] = rs; dinv[node] = rsqrtf((float)(v + 1)); }
    __syncthreads();
    for (int e = lo + t; e < hi; e += 256) {
        unsigned int p = tmp[e];
        int pos = atomicAdd(&cur[p & 255u], 1);
        csr[pos] = (int)(p >> 8);
    }
}

// ---------------- fused W pre-convert: fp32 [K][Nc] -> bf16 transposed [Nc][K] ----------------

__global__ void k_wconv_all(const float* __restrict__ W1, const float* __restrict__ W2,
                            const float* __restrict__ Wf, unsigned short* __restrict__ wb1,
                            unsigned short* __restrict__ wb2, unsigned short* __restrict__ wbf) {
    int i = blockIdx.x * 256 + threadIdx.x;
    if (i < 16384) {
        int k = i >> 7, n = i & 127;
        wb1[n * 128 + k] = f2bf(W1[i]);
    } else if (i < 32768) {
        int j = i - 16384, k = j >> 7, n = j & 127;
        wb2[n * 128 + k] = f2bf(W2[j]);
    } else if (i < 40960) {
        int j = i - 32768, k = j >> 6, n = j & 63;
        wbf[n * 128 + k] = f2bf(Wf[j]);
    }
}

// ---------------- GEMM: out[M,NOUT] = X[M,128] @ W[128,NOUT], K=128 ----------------
// Wbf bf16 pre-transposed [NOUT][128]. X fp32 row-major (XF32) or bf16 row-major.
// Out bf16 row-major or fp32 row-major (OUTF32). Persistent: W staged once per block.

template <int NOUT, bool SCALE, bool BIAS, bool XF32, bool OUTF32>
__global__ __launch_bounds__(256, 2) void k_gemm(
    const void* __restrict__ Xv, const unsigned short* __restrict__ Wbf,
    const float* __restrict__ bias, const float* __restrict__ dinv,
    void* __restrict__ outv, int M, int MB) {
    // Wl[n*136 + k]; stride 136 (272B ≡ 4 banks mod 32 -> 2-way conflict = free)
    __shared__ __align__(16) unsigned short Wl[NOUT * 136];
    int t = threadIdx.x;
    for (int c = t; c < NOUT * 16; c += 256) {
        short8 v = *(const short8*)(Wbf + (size_t)c * 8);
        *(short8*)(&Wl[(c >> 4) * 136 + (c & 15) * 8]) = v;
    }
    __syncthreads();

    int wave = t >> 6, lane = t & 63;
    int quad = lane >> 4, l16 = lane & 15;
    constexpr int NT = NOUT / 16;

    for (int mb = blockIdx.x; mb < MB; mb += gridDim.x) {
        int m0 = mb * 64 + wave * 16;
        int mr = m0 + l16;
        int mrc = mr < M ? mr : M - 1;

        floatx4 acc[NT];
#pragma unroll
        for (int i = 0; i < NT; i++) acc[i] = (floatx4){0.f, 0.f, 0.f, 0.f};

#pragma unroll
        for (int kc = 0; kc < 4; kc++) {
            short8 a;
            if (XF32) {
                const float* X = (const float*)Xv;
                const float* p = X + (size_t)mrc * 128 + kc * 32 + quad * 8;
                float4 xa = *(const float4*)p;
                float4 xb = *(const float4*)(p + 4);
                a[0] = (short)f2bf(xa.x); a[1] = (short)f2bf(xa.y);
                a[2] = (short)f2bf(xa.z); a[3] = (short)f2bf(xa.w);
                a[4] = (short)f2bf(xb.x); a[5] = (short)f2bf(xb.y);
                a[6] = (short)f2bf(xb.z); a[7] = (short)f2bf(xb.w);
            } else {
                const unsigned short* X = (const unsigned short*)Xv;
                a = *(const short8*)(X + (size_t)mrc * 128 + kc * 32 + quad * 8);
            }
#pragma unroll
            for (int nt = 0; nt < NT; nt++) {
                short8 b = *(const short8*)(&Wl[(nt * 16 + l16) * 136 + kc * 32 + quad * 8]);
                acc[nt] = __builtin_amdgcn_mfma_f32_16x16x32_bf16(a, b, acc[nt], 0, 0, 0);
            }
        }

        // C layout: col = l16, row (within 16) = quad*4 + i
#pragma unroll
        for (int i = 0; i < 4; i++) {
            int r = m0 + quad * 4 + i;
            if (r >= M) continue;
            float sc = SCALE ? dinv[r] : 1.0f;
#pragma unroll
            for (int nt = 0; nt < NT; nt++) {
                int n = nt * 16 + l16;
                float v = acc[nt][i] * sc;
                if (BIAS) v += bias[n];
                if (OUTF32) {
                    ((float*)outv)[(size_t)r * NOUT + n] = v;
                } else {
                    ((unsigned short*)outv)[(size_t)r * NOUT + n] = f2bf(v);
                }
            }
        }
    }
}

// ---------------- Aggregation: uint4-gather variant ----------------
// out[d] = relu(dinv[d]*(Hs[d] + sum_nbr Hs[src]) + b). One wave per node.
// lane = grp(4 edge slots) * 16 + c16; lane reads 16B (8 ch) of its group's edge row.
// 4 rows per gather instruction, 1 csr load per 4 edges; xor-reduce over groups at end.

__global__ __launch_bounds__(256, 8) void k_aggregate(
    const unsigned short* __restrict__ Hs, const int* __restrict__ csr,
    const int* __restrict__ row_start,
    const float* __restrict__ dinv, const float* __restrict__ bias,
    unsigned short* __restrict__ out, int N, int E) {
    int wave = threadIdx.x >> 6, lane = threadIdx.x & 63;
    int grp = lane >> 4, c16 = lane & 15;
    int node = blockIdx.x * 4 + wave;
    if (node >= N) return;
    int Nm1 = N - 1;
    int cb = c16 * 8;  // element (channel) base of this lane's 16B chunk

    float a0 = 0.f, a1 = 0.f, a2 = 0.f, a3 = 0.f, a4 = 0.f, a5 = 0.f, a6 = 0.f, a7 = 0.f;

    int start = row_start[node];
    int end = row_start[node + 1];
    if (start < 0) start = 0;
    if (end > E) end = E;
    int cnt = end - start;
    int full4 = cnt >> 2;

    int it = 0;
    for (; it + 2 <= full4; it += 2) {
        int eA = start + it * 4 + grp;
        int eB = eA + 4;
        int iA = min(max(csr[eA], 0), Nm1);
        int iB = min(max(csr[eB], 0), Nm1);
        uint4 uA = *(const uint4*)(Hs + (size_t)iA * 128 + cb);
        uint4 uB = *(const uint4*)(Hs + (size_t)iB * 128 + cb);
        a0 += bflo(uA.x); a1 += bfhi(uA.x); a2 += bflo(uA.y); a3 += bfhi(uA.y);
        a4 += bflo(uA.z); a5 += bfhi(uA.z); a6 += bflo(uA.w); a7 += bfhi(uA.w);
        a0 += bflo(uB.x); a1 += bfhi(uB.x); a2 += bflo(uB.y); a3 += bfhi(uB.y);
        a4 += bflo(uB.z); a5 += bfhi(uB.z); a6 += bflo(uB.w); a7 += bfhi(uB.w);
    }
    for (; it < full4; it++) {
        int eA = start + it * 4 + grp;
        int iA = min(max(csr[eA], 0), Nm1);
        uint4 uA = *(const uint4*)(Hs + (size_t)iA * 128 + cb);
        a0 += bflo(uA.x); a1 += bfhi(uA.x); a2 += bflo(uA.y); a3 += bfhi(uA.y);
        a4 += bflo(uA.z); a5 += bfhi(uA.z); a6 += bflo(uA.w); a7 += bfhi(uA.w);
    }
    int eT = start + full4 * 4 + grp;
    if (eT < end) {  // tail 0-3 edges; divergent across groups only
        int iT = min(max(csr[eT], 0), Nm1);
        uint4 uT = *(const uint4*)(Hs + (size_t)iT * 128 + cb);
        a0 += bflo(uT.x); a1 += bfhi(uT.x); a2 += bflo(uT.y); a3 += bfhi(uT.y);
        a4 += bflo(uT.z); a5 += bfhi(uT.z); a6 += bflo(uT.w); a7 += bfhi(uT.w);
    }

    // reduce over the 4 edge groups (lanes l, l^16, l^32, l^48)
    a0 += __shfl_xor(a0, 16); a1 += __shfl_xor(a1, 16); a2 += __shfl_xor(a2, 16);
    a3 += __shfl_xor(a3, 16); a4 += __shfl_xor(a4, 16); a5 += __shfl_xor(a5, 16);
    a6 += __shfl_xor(a6, 16); a7 += __shfl_xor(a7, 16);
    a0 += __shfl_xor(a0, 32); a1 += __shfl_xor(a1, 32); a2 += __shfl_xor(a2, 32);
    a3 += __shfl_xor(a3, 32); a4 += __shfl_xor(a4, 32); a5 += __shfl_xor(a5, 32);
    a6 += __shfl_xor(a6, 32); a7 += __shfl_xor(a7, 32);

    // self-loop + epilogue (all lanes compute; grp 0 stores)
    uint4 us = *(const uint4*)(Hs + (size_t)node * 128 + cb);
    a0 += bflo(us.x); a1 += bfhi(us.x); a2 += bflo(us.y); a3 += bfhi(us.y);
    a4 += bflo(us.z); a5 += bfhi(us.z); a6 += bflo(us.w); a7 += bfhi(us.w);

    float di = dinv[node];
    float4 b0 = *(const float4*)(bias + cb);
    float4 b1 = *(const float4*)(bias + cb + 4);
    float r0 = fmaxf(fmaf(di, a0, b0.x), 0.f);
    float r1 = fmaxf(fmaf(di, a1, b0.y), 0.f);
    float r2 = fmaxf(fmaf(di, a2, b0.z), 0.f);
    float r3 = fmaxf(fmaf(di, a3, b0.w), 0.f);
    float r4 = fmaxf(fmaf(di, a4, b1.x), 0.f);
    float r5 = fmaxf(fmaf(di, a5, b1.y), 0.f);
    float r6 = fmaxf(fmaf(di, a6, b1.z), 0.f);
    float r7 = fmaxf(fmaf(di, a7, b1.w), 0.f);
    if (grp == 0) {
        uint4 o;
        o.x = (unsigned int)f2bf(r0) | ((unsigned int)f2bf(r1) << 16);
        o.y = (unsigned int)f2bf(r2) | ((unsigned int)f2bf(r3) << 16);
        o.z = (unsigned int)f2bf(r4) | ((unsigned int)f2bf(r5) << 16);
        o.w = (unsigned int)f2bf(r6) | ((unsigned int)f2bf(r7) << 16);
        *(uint4*)(out + (size_t)node * 128 + cb) = o;
    }
}

// ---------------- launch ----------------

extern "C" void kernel_launch(void* const* d_in, const int* in_sizes, int n_in,
                              void* d_out, int out_size, void* d_ws, size_t ws_size,
                              hipStream_t stream) {
    const float* x  = (const float*)d_in[0];
    const int* ei   = (const int*)d_in[1];
    const float* W1 = (const float*)d_in[2];
    const float* b1 = (const float*)d_in[3];
    const float* W2 = (const float*)d_in[4];
    const float* b2 = (const float*)d_in[5];
    const float* Wf = (const float*)d_in[6];
    const float* bf = (const float*)d_in[7];

    int N = in_sizes[0] / 128;
    int E = in_sizes[1] / 2;
    const int* src = ei;
    const int* dst = ei + E;
    int K = (N + BK - 1) / BK;
    if (N >= (1 << 24) || K > 512) return;  // packing/scan assumptions

    size_t need = 0;
    auto pad = [](size_t b) { return (b + 255) & ~(size_t)255; };
    size_t o_bcnt = need; need += pad(512 * 4);
    size_t o_boff = need; need += pad(513 * 4);
    size_t o_bcur = need; need += pad(512 * 4);
    size_t o_rs   = need; need += pad(((size_t)N + 1) * 4);
    size_t o_dinv = need; need += pad((size_t)N * 4);
    size_t o_wbf  = need; need += pad((16384 + 16384 + 8192) * 2);
    size_t o_csr  = need; need += pad((size_t)E * 4);
    size_t o_hs   = need; need += pad((size_t)N * 128 * 2);
    size_t o_a    = need; need += pad((size_t)N * 128 * 2);
    if (ws_size < need) return;
    if ((size_t)E * 4 > (size_t)N * 128 * 2) return;  // tmp must fit in A alias

    char* ws = (char*)d_ws;
    int* bucket_cnt = (int*)(ws + o_bcnt);
    int* bucket_off = (int*)(ws + o_boff);
    int* bucket_cur = (int*)(ws + o_bcur);
    int* row_start  = (int*)(ws + o_rs);
    float* dinv     = (float*)(ws + o_dinv);
    unsigned short* wb1 = (unsigned short*)(ws + o_wbf);
    unsigned short* wb2 = wb1 + 16384;
    unsigned short* wbf = wb2 + 16384;
    int* csr        = (int*)(ws + o_csr);
    unsigned short* Hs = (unsigned short*)(ws + o_hs);
    unsigned short* A  = (unsigned short*)(ws + o_a);
    unsigned int* tmp  = (unsigned int*)A;  // alias: tmp dead before A's first write

    k_wconv_all<<<160, 256, 0, stream>>>(W1, W2, Wf, wb1, wb2, wbf);

    k_zero_cnt<<<2, 256, 0, stream>>>(bucket_cnt, 512);
    k_hist<<<256, 256, 0, stream>>>(dst, bucket_cnt, E, N, K);
    k_scanK<<<1, 512, 0, stream>>>(bucket_cnt, bucket_off, bucket_cur, row_start, K, N);
    k_binscatter<<<256, 256, 0, stream>>>(src, dst, bucket_cur, tmp, E, N, K);
    k_fine<<<K, 256, 0, stream>>>(tmp, bucket_off, row_start, dinv, csr, N);

    int MB = (N + 63) / 64;
    int GG = (MB + 1) / 2;  // persistent: 2 row-tiles per block

    k_gemm<128, true, false, true, false><<<GG, 256, 0, stream>>>(x, wb1, nullptr, dinv, Hs, N, MB);
    k_aggregate<<<(N + 3) / 4, 256, 0, stream>>>(Hs, csr, row_start, dinv, b1, A, N, E);
    k_gemm<128, true, false, false, false><<<GG, 256, 0, stream>>>(A, wb2, nullptr, dinv, Hs, N, MB);
    k_aggregate<<<(N + 3) / 4, 256, 0, stream>>>(Hs, csr, row_start, dinv, b2, A, N, E);
    k_gemm<64, false, true, false, true><<<GG, 256, 0, stream>>>(A, wbf, bf, nullptr, d_out, N, MB);
}